// Round 12
// baseline (24729.770 us; speedup 1.0000x reference)
//
#include <hip/hip_runtime.h>
#include <hip/hip_bf16.h>
#include <stdint.h>
#include <math.h>

#define BB 16
#define QQ 1024
#define TT 512
#define FBIG 1e9f

// ---- XLA CPU f32 tanh (Eigen generic_fast_tanh_float / GenerateVF32Tanh):
// clamp +-7.99881172180175781, tiny-path |x|<0.0004 -> x, FMA-Horner rational
__device__ __forceinline__ float xla_tanhf(float x) {
    if (fabsf(x) < 0.0004f) return x;
    float t = fminf(fmaxf(x, -7.99881172180175781f), 7.99881172180175781f);
    float x2 = t * t;
    float p = fmaf(-2.76076847742355e-16f, x2, 2.00018790482477e-13f); // a13,a11
    p = fmaf(p, x2, -8.60467152213735e-11f);   // a9
    p = fmaf(p, x2, 5.12229709037114e-08f);    // a7
    p = fmaf(p, x2, 1.48572235717979e-05f);    // a5
    p = fmaf(p, x2, 6.37261928875436e-04f);    // a3
    p = fmaf(p, x2, 4.89352455891786e-03f);    // a1
    float num = t * p;
    float q = fmaf(1.19825839466702e-06f, x2, 1.18534705686654e-04f);  // b6,b4
    q = fmaf(q, x2, 2.26843463243900e-03f);    // b2
    q = fmaf(q, x2, 4.89352518554385e-03f);    // b0
    return num / q;
}

// XLA LogisticExpander: logistic(x) = 0.5 + 0.5*tanh(0.5*x)
__device__ __forceinline__ float xla_sigmoid(float x) {
    return 0.5f + 0.5f * xla_tanhf(0.5f * x);
}

// ---- XLA CPU f32 log (GenerateVF32Log, cephes): FMA-Horner, (p*x)*z tail,
// e*q1 / e*q2 fused, -0.5z as mul+sub; 2m-1 via (m-1)+m for small mantissa.
__device__ __forceinline__ float xla_logf(float y) {
    int ix = __float_as_int(y);
    int e = ((ix >> 23) & 0xff) - 126;
    float m = __int_as_float((ix & 0x007fffff) | 0x3f000000);   // [0.5,1)
    bool small = m < 0.707106781186547524f;
    float xm = m - 1.0f;
    if (small) { e -= 1; xm = xm + m; }     // tmp0 = (m-1) + m
    float z = xm * xm;
    float p = 7.0376836292E-2f;
    p = fmaf(p, xm, -1.1514610310E-1f);
    p = fmaf(p, xm, 1.1676998740E-1f);
    p = fmaf(p, xm, -1.2420140846E-1f);
    p = fmaf(p, xm, 1.4249322787E-1f);
    p = fmaf(p, xm, -1.6668057665E-1f);
    p = fmaf(p, xm, 2.0000714765E-1f);
    p = fmaf(p, xm, -2.4999993993E-1f);
    p = fmaf(p, xm, 3.3333331174E-1f);
    float yv = (p * xm) * z;                // (poly*x)*z
    float fe = (float)e;
    yv = fmaf(fe, -2.12194440e-4f, yv);     // y += e*q1
    yv = yv - 0.5f * z;                     // y -= 0.5*z (mul+sub)
    float res = xm + yv;
    res = fmaf(fe, 0.693359375f, res);      // x += e*q2
    return res;
}

// XLA-f32 focal diff: prob via tanh-logistic; **2.0 -> x*x; numpy/HLO order
__device__ __forceinline__ float xla_diff(float x) {
    float pr = xla_sigmoid(x);
    float s  = 1.0f - pr;
    float p2 = pr * pr;
    float s2 = s * s;
    float neg = (0.75f * p2) * (-xla_logf(s + 1e-8f));
    float pos = (0.25f * s2) * (-xla_logf(pr + 1e-8f));
    return pos - neg;
}

// ---- diff (focal class cost term per (b,q,c)) ----------------------------
__global__ void diff_kernel(const float* __restrict__ logits,
                            float* __restrict__ diff, int n) {
    int i = blockIdx.x * blockDim.x + threadIdx.x;
    if (i >= n) return;
    diff[i] = xla_diff(logits[i]);
}

// ---------------- cost matrix C[b][q][t] (t fastest, coalesced) -----------
__global__ void cost_kernel(const float* __restrict__ diff,
                            const float4* __restrict__ pp,
                            const float4* __restrict__ tp,
                            const int* __restrict__ labels,
                            float* __restrict__ Cout, int cls, size_t total) {
    size_t gid = (size_t)blockIdx.x * blockDim.x + threadIdx.x;
    if (gid >= total) return;
    int t = (int)(gid % TT);
    size_t bq = gid / TT;
    int q = (int)(bq % QQ);
    int b = (int)(bq / QQ);
    float4 P = pp[b * QQ + q];
    float4 G = tp[b * TT + t];
    float cp = ((fabsf(P.x - G.x) + fabsf(P.y - G.y)) + fabsf(P.z - G.z)) + fabsf(P.w - G.w);
    int lab = labels[b * TT + t];
    float cc = diff[(size_t)(b * QQ + q) * cls + lab];
    Cout[gid] = cc + cp;
}

// ---- fallback: cost with inline diff (no workspace needed) ---------------
__global__ void cost_inline_kernel(const float* __restrict__ logits,
                                   const float4* __restrict__ pp,
                                   const float4* __restrict__ tp,
                                   const int* __restrict__ labels,
                                   float* __restrict__ Cout, int cls, size_t total) {
    size_t gid = (size_t)blockIdx.x * blockDim.x + threadIdx.x;
    if (gid >= total) return;
    int t = (int)(gid % TT);
    size_t bq = gid / TT;
    int q = (int)(bq % QQ);
    int b = (int)(bq / QQ);
    float4 P = pp[b * QQ + q];
    float4 G = tp[b * TT + t];
    float cp = ((fabsf(P.x - G.x) + fabsf(P.y - G.y)) + fabsf(P.z - G.z)) + fabsf(P.w - G.w);
    int lab = labels[b * TT + t];
    float cc = xla_diff(logits[(size_t)(b * QQ + q) * cls + lab]);
    Cout[gid] = cc + cp;
}

// ---- LAP: one wave per batch, EXACT f32 trajectory mirror ----------------
// Mirror of the reference's f32 while_loop as XLA executes it: per-step f32
// delta updates of u/v/minv in HLO op order, strict-< relax, first-index
// argmin, used-set timing identical. Costs recomputed on the fly with the
// XLA transcendental bits (bit-identical to cost_kernel values).
__global__ __launch_bounds__(64)
void lap_kernel(const float* __restrict__ logits,
                const float4* __restrict__ pp,
                const float4* __restrict__ tp,
                int cls,
                float* __restrict__ out) {
    __shared__ float u[TT];
    __shared__ float diff32[QQ];
    __shared__ float4 pps[QQ];
    __shared__ float4 tps[TT];
    __shared__ int p[QQ];
    __shared__ unsigned short way[QQ];

    int b = blockIdx.x;
    int lane = threadIdx.x;

    for (int j = lane; j < QQ; j += 64) {
        pps[j] = pp[b * QQ + j];
        diff32[j] = xla_diff(logits[(size_t)(b * QQ + j) * cls]);  // cls==1
        p[j] = -1;
    }
    for (int i = lane; i < TT; i += 64) {
        tps[i] = tp[b * TT + i];
        u[i] = 0.0f;
    }
    __syncthreads();

    float v[16];
#pragma unroll
    for (int k = 0; k < 16; ++k) v[k] = 0.0f;

    for (int i = 0; i < TT; ++i) {
        unsigned used = 0;
        float minv[16];
#pragma unroll
        for (int k = 0; k < 16; ++k) minv[k] = FBIG;
        int i0 = i;
        int j0 = QQ;            // dummy column marker (== m)
        int jfree = -1;

        for (;;) {
            float ui0 = u[i0];
            float4 G = tps[i0];
            // relax fresh columns: cur = ((cc + cp) - u[i0]) - v[j], all f32
#pragma unroll
            for (int k = 0; k < 16; ++k) {
                int j = k * 64 + lane;
                float4 P = pps[j];
                float cp = ((fabsf(P.x - G.x) + fabsf(P.y - G.y))
                            + fabsf(P.z - G.z)) + fabsf(P.w - G.w);
                float c = diff32[j] + cp;
                float cur = (c - ui0) - v[k];
                bool fresh = !((used >> k) & 1u);
                if (fresh && cur < minv[k]) {
                    minv[k] = cur;
                    way[j] = (unsigned short)j0;
                }
            }
            // argmin over masked (used -> big), first-index tie-break
            float bv = 2e9f;
            int bj = QQ;
#pragma unroll
            for (int k = 0; k < 16; ++k) {
                float dv = ((used >> k) & 1u) ? FBIG : minv[k];
                if (dv < bv) { bv = dv; bj = k * 64 + lane; }
            }
            for (int off = 32; off >= 1; off >>= 1) {
                float ov = __shfl_xor(bv, off);
                int oj = __shfl_xor(bj, off);
                if (ov < bv || (ov == bv && oj < bj)) { bv = ov; bj = oj; }
            }
            float delta = bv;
            int j1 = bj;

            // per-step updates exactly as reference (used excludes j1):
#pragma unroll
            for (int k = 0; k < 16; ++k) {
                if ((used >> k) & 1u) {
                    v[k] -= delta;
                    int pj = p[k * 64 + lane];
                    u[pj] += delta;
                } else {
                    minv[k] -= delta;
                }
            }
            if (lane == 0) u[i] += delta;

            int pj1 = p[j1];
            if (pj1 < 0) { jfree = j1; break; }
            if (lane == (j1 & 63)) used |= 1u << (j1 >> 6);
            i0 = pj1;
            j0 = j1;
        }

        // augment along predecessor chain (serial, lane 0)
        if (lane == 0) {
            int j = jfree;
            for (;;) {
                int jn = way[j];
                if (jn == QQ) { p[j] = i; break; }
                p[j] = p[jn];
                j = jn;
            }
        }
        __syncthreads();
    }

    // Output: ascending-j compaction == reference argsort(col4row).
    float* outr = out + (size_t)BB * QQ * TT + (size_t)b * TT;
    float* outc = outr + (size_t)BB * TT;
    int base = 0;
    for (int kb = 0; kb < 16; ++kb) {
        int j = kb * 64 + lane;
        int pj = p[j];
        bool a = pj >= 0;
        unsigned long long mask = __ballot(a);
        int rank = __popcll(mask & ((1ull << lane) - 1ull));
        if (a) {
            outr[base + rank] = (float)j;
            outc[base + rank] = (float)pj;
        }
        base += __popcll(mask);
    }
}

extern "C" void kernel_launch(void* const* d_in, const int* in_sizes, int n_in,
                              void* d_out, int out_size, void* d_ws, size_t ws_size,
                              hipStream_t stream) {
    const float* logits = (const float*)d_in[0];
    const float4* pp = (const float4*)d_in[1];
    const float4* tp = (const float4*)d_in[2];
    const int* labels = (const int*)d_in[3];
    float* out = (float*)d_out;

    int cls = in_sizes[0] / (BB * QQ);   // = 1 for this instance
    size_t total = (size_t)BB * QQ * TT;
    size_t diff_bytes = (size_t)in_sizes[0] * sizeof(float);

    if (ws_size >= diff_bytes) {
        float* diff = (float*)d_ws;
        int ndiff = in_sizes[0];
        diff_kernel<<<(ndiff + 255) / 256, 256, 0, stream>>>(logits, diff, ndiff);
        cost_kernel<<<(unsigned)((total + 255) / 256), 256, 0, stream>>>(
            diff, pp, tp, labels, out, cls, total);
    } else {
        cost_inline_kernel<<<(unsigned)((total + 255) / 256), 256, 0, stream>>>(
            logits, pp, tp, labels, out, cls, total);
    }

    lap_kernel<<<BB, 64, 0, stream>>>(logits, pp, tp, cls, out);
}

// Round 15
// 23187.610 us; speedup vs baseline: 1.0665x; 1.0665x over previous
//
#include <hip/hip_runtime.h>
#include <hip/hip_bf16.h>
#include <stdint.h>
#include <math.h>

#define BB 16
#define QQ 1024
#define TT 512
#define FBIG 1e9f

// ---- XLA CPU f32 tanh (Eigen generic_fast_tanh_float / GenerateVF32Tanh):
// clamp +-7.99881172180175781, tiny-path |x|<0.0004 -> x, FMA-Horner rational
__device__ __forceinline__ float xla_tanhf(float x) {
    if (fabsf(x) < 0.0004f) return x;
    float t = fminf(fmaxf(x, -7.99881172180175781f), 7.99881172180175781f);
    float x2 = t * t;
    float p = fmaf(-2.76076847742355e-16f, x2, 2.00018790482477e-13f); // a13,a11
    p = fmaf(p, x2, -8.60467152213735e-11f);   // a9
    p = fmaf(p, x2, 5.12229709037114e-08f);    // a7
    p = fmaf(p, x2, 1.48572235717979e-05f);    // a5
    p = fmaf(p, x2, 6.37261928875436e-04f);    // a3
    p = fmaf(p, x2, 4.89352455891786e-03f);    // a1
    float num = t * p;
    float q = fmaf(1.19825839466702e-06f, x2, 1.18534705686654e-04f);  // b6,b4
    q = fmaf(q, x2, 2.26843463243900e-03f);    // b2
    q = fmaf(q, x2, 4.89352518554385e-03f);    // b0
    return num / q;
}

// XLA LogisticExpander: logistic(x) = 0.5 + 0.5*tanh(0.5*x)
__device__ __forceinline__ float xla_sigmoid(float x) {
    return 0.5f + 0.5f * xla_tanhf(0.5f * x);
}

// ---- XLA CPU f32 log (GenerateVF32Log, cephes): FMA-Horner, (p*x)*z tail,
// e*q1 / e*q2 fused, -0.5z as mul+sub; 2m-1 via (m-1)+m for small mantissa.
__device__ __forceinline__ float xla_logf(float y) {
    int ix = __float_as_int(y);
    int e = ((ix >> 23) & 0xff) - 126;
    float m = __int_as_float((ix & 0x007fffff) | 0x3f000000);   // [0.5,1)
    bool small = m < 0.707106781186547524f;
    float xm = m - 1.0f;
    if (small) { e -= 1; xm = xm + m; }     // tmp0 = (m-1) + m
    float z = xm * xm;
    float p = 7.0376836292E-2f;
    p = fmaf(p, xm, -1.1514610310E-1f);
    p = fmaf(p, xm, 1.1676998740E-1f);
    p = fmaf(p, xm, -1.2420140846E-1f);
    p = fmaf(p, xm, 1.4249322787E-1f);
    p = fmaf(p, xm, -1.6668057665E-1f);
    p = fmaf(p, xm, 2.0000714765E-1f);
    p = fmaf(p, xm, -2.4999993993E-1f);
    p = fmaf(p, xm, 3.3333331174E-1f);
    float yv = (p * xm) * z;                // (poly*x)*z
    float fe = (float)e;
    yv = fmaf(fe, -2.12194440e-4f, yv);     // y += e*q1
    yv = yv - 0.5f * z;                     // y -= 0.5*z (mul+sub)
    float res = xm + yv;
    res = fmaf(fe, 0.693359375f, res);      // x += e*q2
    return res;
}

// XLA-f32 focal diff: prob via tanh-logistic; **2.0 -> x*x; numpy/HLO order
__device__ __forceinline__ float xla_diff(float x) {
    float pr = xla_sigmoid(x);
    float s  = 1.0f - pr;
    float p2 = pr * pr;
    float s2 = s * s;
    float neg = (0.75f * p2) * (-xla_logf(s + 1e-8f));
    float pos = (0.25f * s2) * (-xla_logf(pr + 1e-8f));
    return pos - neg;
}

// ---- diff (focal class cost term per (b,q,c)) ----------------------------
__global__ void diff_kernel(const float* __restrict__ logits,
                            float* __restrict__ diff, int n) {
    int i = blockIdx.x * blockDim.x + threadIdx.x;
    if (i >= n) return;
    diff[i] = xla_diff(logits[i]);
}

// ---------------- cost matrix C[b][q][t] (t fastest, coalesced) -----------
__global__ void cost_kernel(const float* __restrict__ diff,
                            const float4* __restrict__ pp,
                            const float4* __restrict__ tp,
                            const int* __restrict__ labels,
                            float* __restrict__ Cout, int cls, size_t total) {
    size_t gid = (size_t)blockIdx.x * blockDim.x + threadIdx.x;
    if (gid >= total) return;
    int t = (int)(gid % TT);
    size_t bq = gid / TT;
    int q = (int)(bq % QQ);
    int b = (int)(bq / QQ);
    float4 P = pp[b * QQ + q];
    float4 G = tp[b * TT + t];
    float cp = ((fabsf(P.x - G.x) + fabsf(P.y - G.y)) + fabsf(P.z - G.z)) + fabsf(P.w - G.w);
    int lab = labels[b * TT + t];
    float cc = diff[(size_t)(b * QQ + q) * cls + lab];
    Cout[gid] = cc + cp;
}

// ---- fallback: cost with inline diff (no workspace needed) ---------------
__global__ void cost_inline_kernel(const float* __restrict__ logits,
                                   const float4* __restrict__ pp,
                                   const float4* __restrict__ tp,
                                   const int* __restrict__ labels,
                                   float* __restrict__ Cout, int cls, size_t total) {
    size_t gid = (size_t)blockIdx.x * blockDim.x + threadIdx.x;
    if (gid >= total) return;
    int t = (int)(gid % TT);
    size_t bq = gid / TT;
    int q = (int)(bq % QQ);
    int b = (int)(bq / QQ);
    float4 P = pp[b * QQ + q];
    float4 G = tp[b * TT + t];
    float cp = ((fabsf(P.x - G.x) + fabsf(P.y - G.y)) + fabsf(P.z - G.z)) + fabsf(P.w - G.w);
    int lab = labels[b * TT + t];
    float cc = xla_diff(logits[(size_t)(b * QQ + q) * cls + lab]);
    Cout[gid] = cc + cp;
}

// DPP-combine one reduction level of (value, index) lexicographic min.
// Invalid-source lanes receive identity (2e9, INT_MAX) via `old`.
#define DPP_STEP(CTRL)                                                        \
    {                                                                         \
        int s_v = __builtin_amdgcn_update_dpp(idv, bvI, (CTRL), 0xf, 0xf, false); \
        int s_j = __builtin_amdgcn_update_dpp(0x7fffffff, bjI, (CTRL), 0xf, 0xf, false); \
        float fs = __int_as_float(s_v);                                       \
        float fb = __int_as_float(bvI);                                       \
        bool bt = (fs < fb) || (fs == fb && s_j < bjI);                       \
        bvI = bt ? s_v : bvI;                                                 \
        bjI = bt ? s_j : bjI;                                                 \
    }

// ---- LAP: r12 structure (passing) + ONE edit: DPP+readlane argmin
// replacing the 6-level __shfl_xor butterfly (same lexicographic
// (value, first-j) winner). pps/diff32 stay in LDS exactly as r12.
__global__ __launch_bounds__(64)
void lap_kernel(const float* __restrict__ logits,
                const float4* __restrict__ pp,
                const float4* __restrict__ tp,
                int cls,
                float* __restrict__ out) {
    __shared__ float u[TT];
    __shared__ float diff32[QQ];
    __shared__ float4 pps[QQ];
    __shared__ float4 tps[TT];
    __shared__ int p[QQ];
    __shared__ unsigned short way[QQ];

    int b = blockIdx.x;
    int lane = threadIdx.x;

    for (int j = lane; j < QQ; j += 64) {
        pps[j] = pp[b * QQ + j];
        diff32[j] = xla_diff(logits[(size_t)(b * QQ + j) * cls]);  // cls==1
        p[j] = -1;
    }
    for (int i = lane; i < TT; i += 64) {
        tps[i] = tp[b * TT + i];
        u[i] = 0.0f;
    }
    __syncthreads();

    float v[16];
#pragma unroll
    for (int k = 0; k < 16; ++k) v[k] = 0.0f;

    const int idv = __float_as_int(2e9f);

    for (int i = 0; i < TT; ++i) {
        unsigned used = 0;
        float minv[16];
#pragma unroll
        for (int k = 0; k < 16; ++k) minv[k] = FBIG;
        int i0 = i;
        int j0 = QQ;            // dummy column marker (== m)
        int jfree = -1;

        for (;;) {
            float ui0 = u[i0];
            float4 G = tps[i0];
            // relax fresh columns: cur = ((cc + cp) - u[i0]) - v[j], all f32
#pragma unroll
            for (int k = 0; k < 16; ++k) {
                int j = k * 64 + lane;
                float4 P = pps[j];
                float cp = ((fabsf(P.x - G.x) + fabsf(P.y - G.y))
                            + fabsf(P.z - G.z)) + fabsf(P.w - G.w);
                float c = diff32[j] + cp;
                float cur = (c - ui0) - v[k];
                bool fresh = !((used >> k) & 1u);
                if (fresh && cur < minv[k]) {
                    minv[k] = cur;
                    way[j] = (unsigned short)j0;
                }
            }
            // lane-local argmin over masked (used -> big), first-index
            float bv = 2e9f;
            int bj = 0x7fffffff;
#pragma unroll
            for (int k = 0; k < 16; ++k) {
                float dv = ((used >> k) & 1u) ? FBIG : minv[k];
                if (dv < bv) { bv = dv; bj = k * 64 + lane; }
            }
            // 64-lane DPP reduce to lane 63, then broadcast (the ONE edit)
            int bvI = __float_as_int(bv);
            int bjI = bj;
            DPP_STEP(0x111)  // row_shr:1
            DPP_STEP(0x112)  // row_shr:2
            DPP_STEP(0x114)  // row_shr:4
            DPP_STEP(0x118)  // row_shr:8
            DPP_STEP(0x142)  // row_bcast:15
            DPP_STEP(0x143)  // row_bcast:31
            float delta = __int_as_float(__builtin_amdgcn_readlane(bvI, 63));
            int j1 = __builtin_amdgcn_readlane(bjI, 63);

            // per-step updates exactly as reference (used excludes j1):
#pragma unroll
            for (int k = 0; k < 16; ++k) {
                if ((used >> k) & 1u) {
                    v[k] -= delta;
                    int pj = p[k * 64 + lane];
                    u[pj] += delta;
                } else {
                    minv[k] -= delta;
                }
            }
            if (lane == 0) u[i] += delta;

            int pj1 = p[j1];
            if (pj1 < 0) { jfree = j1; break; }
            if (lane == (j1 & 63)) used |= 1u << (j1 >> 6);
            i0 = pj1;
            j0 = j1;
        }

        // augment along predecessor chain (serial, lane 0)
        if (lane == 0) {
            int j = jfree;
            for (;;) {
                int jn = way[j];
                if (jn == QQ) { p[j] = i; break; }
                p[j] = p[jn];
                j = jn;
            }
        }
        __syncthreads();
    }

    // Output: ascending-j compaction == reference argsort(col4row).
    float* outr = out + (size_t)BB * QQ * TT + (size_t)b * TT;
    float* outc = outr + (size_t)BB * TT;
    int base = 0;
    for (int kb = 0; kb < 16; ++kb) {
        int j = kb * 64 + lane;
        int pj = p[j];
        bool a = pj >= 0;
        unsigned long long mask = __ballot(a);
        int rank = __popcll(mask & ((1ull << lane) - 1ull));
        if (a) {
            outr[base + rank] = (float)j;
            outc[base + rank] = (float)pj;
        }
        base += __popcll(mask);
    }
}

extern "C" void kernel_launch(void* const* d_in, const int* in_sizes, int n_in,
                              void* d_out, int out_size, void* d_ws, size_t ws_size,
                              hipStream_t stream) {
    const float* logits = (const float*)d_in[0];
    const float4* pp = (const float4*)d_in[1];
    const float4* tp = (const float4*)d_in[2];
    const int* labels = (const int*)d_in[3];
    float* out = (float*)d_out;

    int cls = in_sizes[0] / (BB * QQ);   // = 1 for this instance
    size_t total = (size_t)BB * QQ * TT;
    size_t diff_bytes = (size_t)in_sizes[0] * sizeof(float);

    if (ws_size >= diff_bytes) {
        float* diff = (float*)d_ws;
        int ndiff = in_sizes[0];
        diff_kernel<<<(ndiff + 255) / 256, 256, 0, stream>>>(logits, diff, ndiff);
        cost_kernel<<<(unsigned)((total + 255) / 256), 256, 0, stream>>>(
            diff, pp, tp, labels, out, cls, total);
    } else {
        cost_inline_kernel<<<(unsigned)((total + 255) / 256), 256, 0, stream>>>(
            logits, pp, tp, labels, out, cls, total);
    }

    lap_kernel<<<BB, 64, 0, stream>>>(logits, pp, tp, cls, out);
}

// Round 16
// 21135.585 us; speedup vs baseline: 1.1701x; 1.0971x over previous
//
#include <hip/hip_runtime.h>
#include <hip/hip_bf16.h>
#include <stdint.h>
#include <math.h>

#define BB 16
#define QQ 1024
#define TT 512
#define FBIG 1e9f

// ---- XLA CPU f32 tanh (Eigen generic_fast_tanh_float / GenerateVF32Tanh):
// clamp +-7.99881172180175781, tiny-path |x|<0.0004 -> x, FMA-Horner rational
__device__ __forceinline__ float xla_tanhf(float x) {
    if (fabsf(x) < 0.0004f) return x;
    float t = fminf(fmaxf(x, -7.99881172180175781f), 7.99881172180175781f);
    float x2 = t * t;
    float p = fmaf(-2.76076847742355e-16f, x2, 2.00018790482477e-13f); // a13,a11
    p = fmaf(p, x2, -8.60467152213735e-11f);   // a9
    p = fmaf(p, x2, 5.12229709037114e-08f);    // a7
    p = fmaf(p, x2, 1.48572235717979e-05f);    // a5
    p = fmaf(p, x2, 6.37261928875436e-04f);    // a3
    p = fmaf(p, x2, 4.89352455891786e-03f);    // a1
    float num = t * p;
    float q = fmaf(1.19825839466702e-06f, x2, 1.18534705686654e-04f);  // b6,b4
    q = fmaf(q, x2, 2.26843463243900e-03f);    // b2
    q = fmaf(q, x2, 4.89352518554385e-03f);    // b0
    return num / q;
}

// XLA LogisticExpander: logistic(x) = 0.5 + 0.5*tanh(0.5*x)
__device__ __forceinline__ float xla_sigmoid(float x) {
    return 0.5f + 0.5f * xla_tanhf(0.5f * x);
}

// ---- XLA CPU f32 log (GenerateVF32Log, cephes): FMA-Horner, (p*x)*z tail,
// e*q1 / e*q2 fused, -0.5z as mul+sub; 2m-1 via (m-1)+m for small mantissa.
__device__ __forceinline__ float xla_logf(float y) {
    int ix = __float_as_int(y);
    int e = ((ix >> 23) & 0xff) - 126;
    float m = __int_as_float((ix & 0x007fffff) | 0x3f000000);   // [0.5,1)
    bool small = m < 0.707106781186547524f;
    float xm = m - 1.0f;
    if (small) { e -= 1; xm = xm + m; }     // tmp0 = (m-1) + m
    float z = xm * xm;
    float p = 7.0376836292E-2f;
    p = fmaf(p, xm, -1.1514610310E-1f);
    p = fmaf(p, xm, 1.1676998740E-1f);
    p = fmaf(p, xm, -1.2420140846E-1f);
    p = fmaf(p, xm, 1.4249322787E-1f);
    p = fmaf(p, xm, -1.6668057665E-1f);
    p = fmaf(p, xm, 2.0000714765E-1f);
    p = fmaf(p, xm, -2.4999993993E-1f);
    p = fmaf(p, xm, 3.3333331174E-1f);
    float yv = (p * xm) * z;                // (poly*x)*z
    float fe = (float)e;
    yv = fmaf(fe, -2.12194440e-4f, yv);     // y += e*q1
    yv = yv - 0.5f * z;                     // y -= 0.5*z (mul+sub)
    float res = xm + yv;
    res = fmaf(fe, 0.693359375f, res);      // x += e*q2
    return res;
}

// XLA-f32 focal diff: prob via tanh-logistic; **2.0 -> x*x; numpy/HLO order
__device__ __forceinline__ float xla_diff(float x) {
    float pr = xla_sigmoid(x);
    float s  = 1.0f - pr;
    float p2 = pr * pr;
    float s2 = s * s;
    float neg = (0.75f * p2) * (-xla_logf(s + 1e-8f));
    float pos = (0.25f * s2) * (-xla_logf(pr + 1e-8f));
    return pos - neg;
}

// ---- diff (focal class cost term per (b,q,c)) ----------------------------
__global__ void diff_kernel(const float* __restrict__ logits,
                            float* __restrict__ diff, int n) {
    int i = blockIdx.x * blockDim.x + threadIdx.x;
    if (i >= n) return;
    diff[i] = xla_diff(logits[i]);
}

// ---------------- cost matrix C[b][q][t] (t fastest, coalesced) -----------
__global__ void cost_kernel(const float* __restrict__ diff,
                            const float4* __restrict__ pp,
                            const float4* __restrict__ tp,
                            const int* __restrict__ labels,
                            float* __restrict__ Cout, int cls, size_t total) {
    size_t gid = (size_t)blockIdx.x * blockDim.x + threadIdx.x;
    if (gid >= total) return;
    int t = (int)(gid % TT);
    size_t bq = gid / TT;
    int q = (int)(bq % QQ);
    int b = (int)(bq / QQ);
    float4 P = pp[b * QQ + q];
    float4 G = tp[b * TT + t];
    float cp = ((fabsf(P.x - G.x) + fabsf(P.y - G.y)) + fabsf(P.z - G.z)) + fabsf(P.w - G.w);
    int lab = labels[b * TT + t];
    float cc = diff[(size_t)(b * QQ + q) * cls + lab];
    Cout[gid] = cc + cp;
}

// ---- fallback: cost with inline diff (no workspace needed) ---------------
__global__ void cost_inline_kernel(const float* __restrict__ logits,
                                   const float4* __restrict__ pp,
                                   const float4* __restrict__ tp,
                                   const int* __restrict__ labels,
                                   float* __restrict__ Cout, int cls, size_t total) {
    size_t gid = (size_t)blockIdx.x * blockDim.x + threadIdx.x;
    if (gid >= total) return;
    int t = (int)(gid % TT);
    size_t bq = gid / TT;
    int q = (int)(bq % QQ);
    int b = (int)(bq / QQ);
    float4 P = pp[b * QQ + q];
    float4 G = tp[b * TT + t];
    float cp = ((fabsf(P.x - G.x) + fabsf(P.y - G.y)) + fabsf(P.z - G.z)) + fabsf(P.w - G.w);
    int lab = labels[b * TT + t];
    float cc = xla_diff(logits[(size_t)(b * QQ + q) * cls + lab]);
    Cout[gid] = cc + cp;
}

// DPP-combine one reduction level of (value, meta) lexicographic min.
// Invalid-source lanes receive identity (2e9, 0xFFFFFFFF) via `old`.
#define DPP_STEP(CTRL)                                                        \
    {                                                                         \
        int s_v = __builtin_amdgcn_update_dpp(idv, bvI, (CTRL), 0xf, 0xf, false); \
        int s_m = __builtin_amdgcn_update_dpp(-1, (int)bmU, (CTRL), 0xf, 0xf, false); \
        float fs = __int_as_float(s_v);                                       \
        float fb = __int_as_float(bvI);                                       \
        bool bt = (fs < fb) || (fs == fb && (unsigned)s_m < bmU);             \
        bvI = bt ? s_v : bvI;                                                 \
        bmU = bt ? (unsigned)s_m : bmU;                                       \
    }

// ---- LAP: r15 structure (passing) + ONE edit: phase-start p_cache[16] and
// DPP meta payload (j<<10)|(p[j]+1). Removes the dependent p[j1] LDS read
// from the step chain and the 16 ds_read_b32 of p per step. p is
// phase-constant (augment writes only at phase end), so values identical.
// pps/diff32/u/way LDS layout & per-step u RMW verbatim r15.
__global__ __launch_bounds__(64)
void lap_kernel(const float* __restrict__ logits,
                const float4* __restrict__ pp,
                const float4* __restrict__ tp,
                int cls,
                float* __restrict__ out) {
    __shared__ float u[TT];
    __shared__ float diff32[QQ];
    __shared__ float4 pps[QQ];
    __shared__ float4 tps[TT];
    __shared__ int p[QQ];
    __shared__ unsigned short way[QQ];

    int b = blockIdx.x;
    int lane = threadIdx.x;

    for (int j = lane; j < QQ; j += 64) {
        pps[j] = pp[b * QQ + j];
        diff32[j] = xla_diff(logits[(size_t)(b * QQ + j) * cls]);  // cls==1
        p[j] = -1;
    }
    for (int i = lane; i < TT; i += 64) {
        tps[i] = tp[b * TT + i];
        u[i] = 0.0f;
    }
    __syncthreads();

    float v[16];
#pragma unroll
    for (int k = 0; k < 16; ++k) v[k] = 0.0f;

    const int idv = __float_as_int(2e9f);

    for (int i = 0; i < TT; ++i) {
        unsigned used = 0;
        float minv[16];
        int p_cache[16];
        unsigned meta[16];
#pragma unroll
        for (int k = 0; k < 16; ++k) {
            minv[k] = FBIG;
            p_cache[k] = p[k * 64 + lane];          // phase-constant
            meta[k] = ((unsigned)(k * 64 + lane) << 10) | (unsigned)(p_cache[k] + 1);
        }
        int i0 = i;
        int j0 = QQ;            // dummy column marker (== m)
        int jfree = -1;

        for (;;) {
            float ui0 = u[i0];
            float4 G = tps[i0];
            // relax fresh columns: cur = ((cc + cp) - u[i0]) - v[j], all f32
#pragma unroll
            for (int k = 0; k < 16; ++k) {
                int j = k * 64 + lane;
                float4 P = pps[j];
                float cp = ((fabsf(P.x - G.x) + fabsf(P.y - G.y))
                            + fabsf(P.z - G.z)) + fabsf(P.w - G.w);
                float c = diff32[j] + cp;
                float cur = (c - ui0) - v[k];
                bool fresh = !((used >> k) & 1u);
                if (fresh && cur < minv[k]) {
                    minv[k] = cur;
                    way[j] = (unsigned short)j0;
                }
            }
            // lane-local argmin over masked (used -> big); ascending-k scan
            // with strict < => first-index winner, meta tags along
            float bv = 2e9f;
            unsigned bm = 0xFFFFFFFFu;
#pragma unroll
            for (int k = 0; k < 16; ++k) {
                float dv = ((used >> k) & 1u) ? FBIG : minv[k];
                if (dv < bv) { bv = dv; bm = meta[k]; }
            }
            // 64-lane DPP reduce to lane 63, then broadcast
            int bvI = __float_as_int(bv);
            unsigned bmU = bm;
            DPP_STEP(0x111)  // row_shr:1
            DPP_STEP(0x112)  // row_shr:2
            DPP_STEP(0x114)  // row_shr:4
            DPP_STEP(0x118)  // row_shr:8
            DPP_STEP(0x142)  // row_bcast:15
            DPP_STEP(0x143)  // row_bcast:31
            float delta = __int_as_float(__builtin_amdgcn_readlane(bvI, 63));
            unsigned wm = (unsigned)__builtin_amdgcn_readlane((int)bmU, 63);
            int j1 = (int)(wm >> 10);
            int pj1 = (int)(wm & 1023u) - 1;

            // per-step updates exactly as reference (used excludes j1):
#pragma unroll
            for (int k = 0; k < 16; ++k) {
                if ((used >> k) & 1u) {
                    v[k] -= delta;
                    u[p_cache[k]] += delta;
                } else {
                    minv[k] -= delta;
                }
            }
            if (lane == 0) u[i] += delta;

            if (pj1 < 0) { jfree = j1; break; }
            if (lane == (j1 & 63)) used |= 1u << (j1 >> 6);
            i0 = pj1;
            j0 = j1;
        }

        // augment along predecessor chain (serial, lane 0)
        if (lane == 0) {
            int j = jfree;
            for (;;) {
                int jn = way[j];
                if (jn == QQ) { p[j] = i; break; }
                p[j] = p[jn];
                j = jn;
            }
        }
        __syncthreads();
    }

    // Output: ascending-j compaction == reference argsort(col4row).
    float* outr = out + (size_t)BB * QQ * TT + (size_t)b * TT;
    float* outc = outr + (size_t)BB * TT;
    int base = 0;
    for (int kb = 0; kb < 16; ++kb) {
        int j = kb * 64 + lane;
        int pj = p[j];
        bool a = pj >= 0;
        unsigned long long mask = __ballot(a);
        int rank = __popcll(mask & ((1ull << lane) - 1ull));
        if (a) {
            outr[base + rank] = (float)j;
            outc[base + rank] = (float)pj;
        }
        base += __popcll(mask);
    }
}

extern "C" void kernel_launch(void* const* d_in, const int* in_sizes, int n_in,
                              void* d_out, int out_size, void* d_ws, size_t ws_size,
                              hipStream_t stream) {
    const float* logits = (const float*)d_in[0];
    const float4* pp = (const float4*)d_in[1];
    const float4* tp = (const float4*)d_in[2];
    const int* labels = (const int*)d_in[3];
    float* out = (float*)d_out;

    int cls = in_sizes[0] / (BB * QQ);   // = 1 for this instance
    size_t total = (size_t)BB * QQ * TT;
    size_t diff_bytes = (size_t)in_sizes[0] * sizeof(float);

    if (ws_size >= diff_bytes) {
        float* diff = (float*)d_ws;
        int ndiff = in_sizes[0];
        diff_kernel<<<(ndiff + 255) / 256, 256, 0, stream>>>(logits, diff, ndiff);
        cost_kernel<<<(unsigned)((total + 255) / 256), 256, 0, stream>>>(
            diff, pp, tp, labels, out, cls, total);
    } else {
        cost_inline_kernel<<<(unsigned)((total + 255) / 256), 256, 0, stream>>>(
            logits, pp, tp, labels, out, cls, total);
    }

    lap_kernel<<<BB, 64, 0, stream>>>(logits, pp, tp, cls, out);
}

// Round 17
// 17552.582 us; speedup vs baseline: 1.4089x; 1.2041x over previous
//
#include <hip/hip_runtime.h>
#include <hip/hip_bf16.h>
#include <stdint.h>
#include <math.h>

#define BB 16
#define QQ 1024
#define TT 512
#define FBIG 1e9f

// ---- XLA CPU f32 tanh (Eigen generic_fast_tanh_float / GenerateVF32Tanh):
// clamp +-7.99881172180175781, tiny-path |x|<0.0004 -> x, FMA-Horner rational
__device__ __forceinline__ float xla_tanhf(float x) {
    if (fabsf(x) < 0.0004f) return x;
    float t = fminf(fmaxf(x, -7.99881172180175781f), 7.99881172180175781f);
    float x2 = t * t;
    float p = fmaf(-2.76076847742355e-16f, x2, 2.00018790482477e-13f); // a13,a11
    p = fmaf(p, x2, -8.60467152213735e-11f);   // a9
    p = fmaf(p, x2, 5.12229709037114e-08f);    // a7
    p = fmaf(p, x2, 1.48572235717979e-05f);    // a5
    p = fmaf(p, x2, 6.37261928875436e-04f);    // a3
    p = fmaf(p, x2, 4.89352455891786e-03f);    // a1
    float num = t * p;
    float q = fmaf(1.19825839466702e-06f, x2, 1.18534705686654e-04f);  // b6,b4
    q = fmaf(q, x2, 2.26843463243900e-03f);    // b2
    q = fmaf(q, x2, 4.89352518554385e-03f);    // b0
    return num / q;
}

// XLA LogisticExpander: logistic(x) = 0.5 + 0.5*tanh(0.5*x)
__device__ __forceinline__ float xla_sigmoid(float x) {
    return 0.5f + 0.5f * xla_tanhf(0.5f * x);
}

// ---- XLA CPU f32 log (GenerateVF32Log, cephes): FMA-Horner, (p*x)*z tail,
// e*q1 / e*q2 fused, -0.5z as mul+sub; 2m-1 via (m-1)+m for small mantissa.
__device__ __forceinline__ float xla_logf(float y) {
    int ix = __float_as_int(y);
    int e = ((ix >> 23) & 0xff) - 126;
    float m = __int_as_float((ix & 0x007fffff) | 0x3f000000);   // [0.5,1)
    bool small = m < 0.707106781186547524f;
    float xm = m - 1.0f;
    if (small) { e -= 1; xm = xm + m; }     // tmp0 = (m-1) + m
    float z = xm * xm;
    float p = 7.0376836292E-2f;
    p = fmaf(p, xm, -1.1514610310E-1f);
    p = fmaf(p, xm, 1.1676998740E-1f);
    p = fmaf(p, xm, -1.2420140846E-1f);
    p = fmaf(p, xm, 1.4249322787E-1f);
    p = fmaf(p, xm, -1.6668057665E-1f);
    p = fmaf(p, xm, 2.0000714765E-1f);
    p = fmaf(p, xm, -2.4999993993E-1f);
    p = fmaf(p, xm, 3.3333331174E-1f);
    float yv = (p * xm) * z;                // (poly*x)*z
    float fe = (float)e;
    yv = fmaf(fe, -2.12194440e-4f, yv);     // y += e*q1
    yv = yv - 0.5f * z;                     // y -= 0.5*z (mul+sub)
    float res = xm + yv;
    res = fmaf(fe, 0.693359375f, res);      // x += e*q2
    return res;
}

// XLA-f32 focal diff: prob via tanh-logistic; **2.0 -> x*x; numpy/HLO order
__device__ __forceinline__ float xla_diff(float x) {
    float pr = xla_sigmoid(x);
    float s  = 1.0f - pr;
    float p2 = pr * pr;
    float s2 = s * s;
    float neg = (0.75f * p2) * (-xla_logf(s + 1e-8f));
    float pos = (0.25f * s2) * (-xla_logf(pr + 1e-8f));
    return pos - neg;
}

// ---- diff (focal class cost term per (b,q,c)) ----------------------------
__global__ void diff_kernel(const float* __restrict__ logits,
                            float* __restrict__ diff, int n) {
    int i = blockIdx.x * blockDim.x + threadIdx.x;
    if (i >= n) return;
    diff[i] = xla_diff(logits[i]);
}

// ---------------- cost matrix C[b][q][t] (t fastest, coalesced) -----------
__global__ void cost_kernel(const float* __restrict__ diff,
                            const float4* __restrict__ pp,
                            const float4* __restrict__ tp,
                            const int* __restrict__ labels,
                            float* __restrict__ Cout, int cls, size_t total) {
    size_t gid = (size_t)blockIdx.x * blockDim.x + threadIdx.x;
    if (gid >= total) return;
    int t = (int)(gid % TT);
    size_t bq = gid / TT;
    int q = (int)(bq % QQ);
    int b = (int)(bq / QQ);
    float4 P = pp[b * QQ + q];
    float4 G = tp[b * TT + t];
    float cp = ((fabsf(P.x - G.x) + fabsf(P.y - G.y)) + fabsf(P.z - G.z)) + fabsf(P.w - G.w);
    int lab = labels[b * TT + t];
    float cc = diff[(size_t)(b * QQ + q) * cls + lab];
    Cout[gid] = cc + cp;
}

// ---- fallback: cost with inline diff (no workspace needed) ---------------
__global__ void cost_inline_kernel(const float* __restrict__ logits,
                                   const float4* __restrict__ pp,
                                   const float4* __restrict__ tp,
                                   const int* __restrict__ labels,
                                   float* __restrict__ Cout, int cls, size_t total) {
    size_t gid = (size_t)blockIdx.x * blockDim.x + threadIdx.x;
    if (gid >= total) return;
    int t = (int)(gid % TT);
    size_t bq = gid / TT;
    int q = (int)(bq % QQ);
    int b = (int)(bq / QQ);
    float4 P = pp[b * QQ + q];
    float4 G = tp[b * TT + t];
    float cp = ((fabsf(P.x - G.x) + fabsf(P.y - G.y)) + fabsf(P.z - G.z)) + fabsf(P.w - G.w);
    int lab = labels[b * TT + t];
    float cc = xla_diff(logits[(size_t)(b * QQ + q) * cls + lab]);
    Cout[gid] = cc + cp;
}

// DPP-combine one reduction level of (value, meta) lexicographic min.
// Invalid-source lanes receive identity (2e9, 0xFFFFFFFF) via `old`.
#define DPP_STEP(CTRL)                                                        \
    {                                                                         \
        int s_v = __builtin_amdgcn_update_dpp(idv, bvI, (CTRL), 0xf, 0xf, false); \
        int s_m = __builtin_amdgcn_update_dpp(-1, (int)bmU, (CTRL), 0xf, 0xf, false); \
        float fs = __int_as_float(s_v);                                       \
        float fb = __int_as_float(bvI);                                       \
        bool bt = (fs < fb) || (fs == fb && (unsigned)s_m < bmU);             \
        bvI = bt ? s_v : bvI;                                                 \
        bmU = bt ? (unsigned)s_m : bmU;                                       \
    }

// ---- LAP: r16 structure (passing) + ONE edit-set: in-phase u in registers.
// Within a phase, u[pj1] is never dirtied before column j1 is selected
// (u-adds cover only used columns' rows), so: (i) u[pj1]/tps[pj1] read
// early — right after readlane — overlapping the update loop; (ii) each
// used column's row-u accumulates in uacc[k] snapshotted from the
// broadcast nui ((u0+d1)+d2..., exact reference f32 cell sequence), flushed
// once at phase end; (iii) u[i] RMW -> uu_i register, flushed at phase end.
// pps/diff32/way LDS layout & relax verbatim r16.
__global__ __launch_bounds__(64)
void lap_kernel(const float* __restrict__ logits,
                const float4* __restrict__ pp,
                const float4* __restrict__ tp,
                int cls,
                float* __restrict__ out) {
    __shared__ float u[TT];
    __shared__ float diff32[QQ];
    __shared__ float4 pps[QQ];
    __shared__ float4 tps[TT];
    __shared__ int p[QQ];
    __shared__ unsigned short way[QQ];

    int b = blockIdx.x;
    int lane = threadIdx.x;

    for (int j = lane; j < QQ; j += 64) {
        pps[j] = pp[b * QQ + j];
        diff32[j] = xla_diff(logits[(size_t)(b * QQ + j) * cls]);  // cls==1
        p[j] = -1;
    }
    for (int i = lane; i < TT; i += 64) {
        tps[i] = tp[b * TT + i];
        u[i] = 0.0f;
    }
    __syncthreads();

    float v[16];
#pragma unroll
    for (int k = 0; k < 16; ++k) v[k] = 0.0f;

    const int idv = __float_as_int(2e9f);

    for (int i = 0; i < TT; ++i) {
        unsigned used = 0;
        float minv[16], uacc[16];
        int p_cache[16];
        unsigned meta[16];
#pragma unroll
        for (int k = 0; k < 16; ++k) {
            minv[k] = FBIG;
            uacc[k] = 0.0f;
            p_cache[k] = p[k * 64 + lane];          // phase-constant
            meta[k] = ((unsigned)(k * 64 + lane) << 10) | (unsigned)(p_cache[k] + 1);
        }
        int j0 = QQ;            // dummy column marker (== m)
        int jfree = -1;
        float ui0 = u[i];       // phase-start u of the new row
        float uu_i = ui0;       // running u[i] (dummy column's row)
        float4 G = tps[i];

        for (;;) {
            // relax fresh columns: cur = ((cc + cp) - u[i0]) - v[j], all f32
#pragma unroll
            for (int k = 0; k < 16; ++k) {
                int j = k * 64 + lane;
                float4 P = pps[j];
                float cp = ((fabsf(P.x - G.x) + fabsf(P.y - G.y))
                            + fabsf(P.z - G.z)) + fabsf(P.w - G.w);
                float c = diff32[j] + cp;
                float cur = (c - ui0) - v[k];
                bool fresh = !((used >> k) & 1u);
                if (fresh && cur < minv[k]) {
                    minv[k] = cur;
                    way[j] = (unsigned short)j0;
                }
            }
            // lane-local argmin over masked (used -> big); ascending-k scan
            float bv = 2e9f;
            unsigned bm = 0xFFFFFFFFu;
#pragma unroll
            for (int k = 0; k < 16; ++k) {
                float dv = ((used >> k) & 1u) ? FBIG : minv[k];
                if (dv < bv) { bv = dv; bm = meta[k]; }
            }
            // 64-lane DPP reduce to lane 63, then broadcast
            int bvI = __float_as_int(bv);
            unsigned bmU = bm;
            DPP_STEP(0x111)  // row_shr:1
            DPP_STEP(0x112)  // row_shr:2
            DPP_STEP(0x114)  // row_shr:4
            DPP_STEP(0x118)  // row_shr:8
            DPP_STEP(0x142)  // row_bcast:15
            DPP_STEP(0x143)  // row_bcast:31
            float delta = __int_as_float(__builtin_amdgcn_readlane(bvI, 63));
            unsigned wm = (unsigned)__builtin_amdgcn_readlane((int)bmU, 63);
            int j1 = (int)(wm >> 10);
            int pj1 = (int)(wm & 1023u) - 1;
            bool matched = (pj1 >= 0);

            // early uniform reads for next step (phase-start values; u[pj1]
            // is untouched in-phase before j1's selection) — latency
            // overlaps the register update loop below
            float nui = 0.0f; float4 nG = G;
            if (matched) { nui = u[pj1]; nG = tps[pj1]; }

            // per-step updates exactly as reference (used excludes j1):
#pragma unroll
            for (int k = 0; k < 16; ++k) {
                if ((used >> k) & 1u) {
                    v[k] -= delta;
                    uacc[k] += delta;
                } else {
                    minv[k] -= delta;
                }
            }
            uu_i += delta;

            if (!matched) { jfree = j1; break; }

            // mark j1 used; snapshot its row's phase-start u into uacc
            unsigned selbit = (lane == (j1 & 63)) ? (1u << (j1 >> 6)) : 0u;
#pragma unroll
            for (int k = 0; k < 16; ++k)
                uacc[k] = ((selbit >> k) & 1u) ? nui : uacc[k];
            used |= selbit;
            j0 = j1;
            ui0 = nui;
            G = nG;
        }

        // phase epilogue: flush u for used columns' rows + dummy row
#pragma unroll
        for (int k = 0; k < 16; ++k) {
            if ((used >> k) & 1u) u[p_cache[k]] = uacc[k];
        }
        if (lane == 0) u[i] = uu_i;

        // augment along predecessor chain (serial, lane 0)
        if (lane == 0) {
            int j = jfree;
            for (;;) {
                int jn = way[j];
                if (jn == QQ) { p[j] = i; break; }
                p[j] = p[jn];
                j = jn;
            }
        }
        __syncthreads();
    }

    // Output: ascending-j compaction == reference argsort(col4row).
    float* outr = out + (size_t)BB * QQ * TT + (size_t)b * TT;
    float* outc = outr + (size_t)BB * TT;
    int base = 0;
    for (int kb = 0; kb < 16; ++kb) {
        int j = kb * 64 + lane;
        int pj = p[j];
        bool a = pj >= 0;
        unsigned long long mask = __ballot(a);
        int rank = __popcll(mask & ((1ull << lane) - 1ull));
        if (a) {
            outr[base + rank] = (float)j;
            outc[base + rank] = (float)pj;
        }
        base += __popcll(mask);
    }
}

extern "C" void kernel_launch(void* const* d_in, const int* in_sizes, int n_in,
                              void* d_out, int out_size, void* d_ws, size_t ws_size,
                              hipStream_t stream) {
    const float* logits = (const float*)d_in[0];
    const float4* pp = (const float4*)d_in[1];
    const float4* tp = (const float4*)d_in[2];
    const int* labels = (const int*)d_in[3];
    float* out = (float*)d_out;

    int cls = in_sizes[0] / (BB * QQ);   // = 1 for this instance
    size_t total = (size_t)BB * QQ * TT;
    size_t diff_bytes = (size_t)in_sizes[0] * sizeof(float);

    if (ws_size >= diff_bytes) {
        float* diff = (float*)d_ws;
        int ndiff = in_sizes[0];
        diff_kernel<<<(ndiff + 255) / 256, 256, 0, stream>>>(logits, diff, ndiff);
        cost_kernel<<<(unsigned)((total + 255) / 256), 256, 0, stream>>>(
            diff, pp, tp, labels, out, cls, total);
    } else {
        cost_inline_kernel<<<(unsigned)((total + 255) / 256), 256, 0, stream>>>(
            logits, pp, tp, labels, out, cls, total);
    }

    lap_kernel<<<BB, 64, 0, stream>>>(logits, pp, tp, cls, out);
}

// Round 18
// 11580.468 us; speedup vs baseline: 2.1355x; 1.5157x over previous
//
#include <hip/hip_runtime.h>
#include <hip/hip_bf16.h>
#include <stdint.h>
#include <math.h>

#define BB 16
#define QQ 1024
#define TT 512
#define FBIG 1e9f

// ---- XLA CPU f32 tanh (Eigen generic_fast_tanh_float / GenerateVF32Tanh):
// clamp +-7.99881172180175781, tiny-path |x|<0.0004 -> x, FMA-Horner rational
__device__ __forceinline__ float xla_tanhf(float x) {
    if (fabsf(x) < 0.0004f) return x;
    float t = fminf(fmaxf(x, -7.99881172180175781f), 7.99881172180175781f);
    float x2 = t * t;
    float p = fmaf(-2.76076847742355e-16f, x2, 2.00018790482477e-13f); // a13,a11
    p = fmaf(p, x2, -8.60467152213735e-11f);   // a9
    p = fmaf(p, x2, 5.12229709037114e-08f);    // a7
    p = fmaf(p, x2, 1.48572235717979e-05f);    // a5
    p = fmaf(p, x2, 6.37261928875436e-04f);    // a3
    p = fmaf(p, x2, 4.89352455891786e-03f);    // a1
    float num = t * p;
    float q = fmaf(1.19825839466702e-06f, x2, 1.18534705686654e-04f);  // b6,b4
    q = fmaf(q, x2, 2.26843463243900e-03f);    // b2
    q = fmaf(q, x2, 4.89352518554385e-03f);    // b0
    return num / q;
}

// XLA LogisticExpander: logistic(x) = 0.5 + 0.5*tanh(0.5*x)
__device__ __forceinline__ float xla_sigmoid(float x) {
    return 0.5f + 0.5f * xla_tanhf(0.5f * x);
}

// ---- XLA CPU f32 log (GenerateVF32Log, cephes): FMA-Horner, (p*x)*z tail,
// e*q1 / e*q2 fused, -0.5z as mul+sub; 2m-1 via (m-1)+m for small mantissa.
__device__ __forceinline__ float xla_logf(float y) {
    int ix = __float_as_int(y);
    int e = ((ix >> 23) & 0xff) - 126;
    float m = __int_as_float((ix & 0x007fffff) | 0x3f000000);   // [0.5,1)
    bool small = m < 0.707106781186547524f;
    float xm = m - 1.0f;
    if (small) { e -= 1; xm = xm + m; }     // tmp0 = (m-1) + m
    float z = xm * xm;
    float p = 7.0376836292E-2f;
    p = fmaf(p, xm, -1.1514610310E-1f);
    p = fmaf(p, xm, 1.1676998740E-1f);
    p = fmaf(p, xm, -1.2420140846E-1f);
    p = fmaf(p, xm, 1.4249322787E-1f);
    p = fmaf(p, xm, -1.6668057665E-1f);
    p = fmaf(p, xm, 2.0000714765E-1f);
    p = fmaf(p, xm, -2.4999993993E-1f);
    p = fmaf(p, xm, 3.3333331174E-1f);
    float yv = (p * xm) * z;                // (poly*x)*z
    float fe = (float)e;
    yv = fmaf(fe, -2.12194440e-4f, yv);     // y += e*q1
    yv = yv - 0.5f * z;                     // y -= 0.5*z (mul+sub)
    float res = xm + yv;
    res = fmaf(fe, 0.693359375f, res);      // x += e*q2
    return res;
}

// XLA-f32 focal diff: prob via tanh-logistic; **2.0 -> x*x; numpy/HLO order
__device__ __forceinline__ float xla_diff(float x) {
    float pr = xla_sigmoid(x);
    float s  = 1.0f - pr;
    float p2 = pr * pr;
    float s2 = s * s;
    float neg = (0.75f * p2) * (-xla_logf(s + 1e-8f));
    float pos = (0.25f * s2) * (-xla_logf(pr + 1e-8f));
    return pos - neg;
}

// ---- diff (focal class cost term per (b,q,c)) ----------------------------
__global__ void diff_kernel(const float* __restrict__ logits,
                            float* __restrict__ diff, int n) {
    int i = blockIdx.x * blockDim.x + threadIdx.x;
    if (i >= n) return;
    diff[i] = xla_diff(logits[i]);
}

// ---------------- cost matrix C[b][q][t] (t fastest, coalesced) -----------
__global__ void cost_kernel(const float* __restrict__ diff,
                            const float4* __restrict__ pp,
                            const float4* __restrict__ tp,
                            const int* __restrict__ labels,
                            float* __restrict__ Cout, int cls, size_t total) {
    size_t gid = (size_t)blockIdx.x * blockDim.x + threadIdx.x;
    if (gid >= total) return;
    int t = (int)(gid % TT);
    size_t bq = gid / TT;
    int q = (int)(bq % QQ);
    int b = (int)(bq / QQ);
    float4 P = pp[b * QQ + q];
    float4 G = tp[b * TT + t];
    float cp = ((fabsf(P.x - G.x) + fabsf(P.y - G.y)) + fabsf(P.z - G.z)) + fabsf(P.w - G.w);
    int lab = labels[b * TT + t];
    float cc = diff[(size_t)(b * QQ + q) * cls + lab];
    Cout[gid] = cc + cp;
}

// ---- fallback: cost with inline diff (no workspace needed) ---------------
__global__ void cost_inline_kernel(const float* __restrict__ logits,
                                   const float4* __restrict__ pp,
                                   const float4* __restrict__ tp,
                                   const int* __restrict__ labels,
                                   float* __restrict__ Cout, int cls, size_t total) {
    size_t gid = (size_t)blockIdx.x * blockDim.x + threadIdx.x;
    if (gid >= total) return;
    int t = (int)(gid % TT);
    size_t bq = gid / TT;
    int q = (int)(bq % QQ);
    int b = (int)(bq / QQ);
    float4 P = pp[b * QQ + q];
    float4 G = tp[b * TT + t];
    float cp = ((fabsf(P.x - G.x) + fabsf(P.y - G.y)) + fabsf(P.z - G.z)) + fabsf(P.w - G.w);
    int lab = labels[b * TT + t];
    float cc = xla_diff(logits[(size_t)(b * QQ + q) * cls + lab]);
    Cout[gid] = cc + cp;
}

// DPP-combine one reduction level of (value, meta) lexicographic min.
// Invalid-source lanes receive identity (2e9, 0xFFFFFFFF) via `old`.
#define DPP_STEP(CTRL)                                                        \
    {                                                                         \
        int s_v = __builtin_amdgcn_update_dpp(idv, bvI, (CTRL), 0xf, 0xf, false); \
        int s_m = __builtin_amdgcn_update_dpp(-1, (int)bmU, (CTRL), 0xf, 0xf, false); \
        float fs = __int_as_float(s_v);                                       \
        float fb = __int_as_float(bvI);                                       \
        bool bt = (fs < fb) || (fs == fb && (unsigned)s_m < bmU);             \
        bvI = bt ? s_v : bvI;                                                 \
        bmU = bt ? (unsigned)s_m : bmU;                                       \
    }

// ---- LAP: r17 structure (passing) + two residency edits:
//  (1) diff32 -> dreg[16] registers (loaded ONCE from LDS after staging
//      sync; kernel-constant per (k,lane); removes 16 ds_read_b32/step)
//  (2) way -> wayr[16] registers (cndmask updates; flushed at phase end
//      for used columns + jfree — exact coverage of the augment chain;
//      removes 16 conditional ds_write_b16/step)
// f32 op sequence / argmin winner / update order untouched (bit-exact).
__global__ __launch_bounds__(64)
void lap_kernel(const float* __restrict__ logits,
                const float4* __restrict__ pp,
                const float4* __restrict__ tp,
                int cls,
                float* __restrict__ out) {
    __shared__ float u[TT];
    __shared__ float diff32[QQ];
    __shared__ float4 pps[QQ];
    __shared__ float4 tps[TT];
    __shared__ int p[QQ];
    __shared__ unsigned short way[QQ];

    int b = blockIdx.x;
    int lane = threadIdx.x;

    for (int j = lane; j < QQ; j += 64) {
        pps[j] = pp[b * QQ + j];
        diff32[j] = xla_diff(logits[(size_t)(b * QQ + j) * cls]);  // cls==1
        p[j] = -1;
    }
    for (int i = lane; i < TT; i += 64) {
        tps[i] = tp[b * TT + i];
        u[i] = 0.0f;
    }
    __syncthreads();

    // (1) kernel-constant per-lane diff values: LDS -> registers, once
    float dreg[16];
#pragma unroll
    for (int k = 0; k < 16; ++k) dreg[k] = diff32[k * 64 + lane];

    float v[16];
#pragma unroll
    for (int k = 0; k < 16; ++k) v[k] = 0.0f;

    const int idv = __float_as_int(2e9f);

    for (int i = 0; i < TT; ++i) {
        unsigned used = 0;
        float minv[16], uacc[16];
        unsigned wayr[16];
        int p_cache[16];
        unsigned meta[16];
#pragma unroll
        for (int k = 0; k < 16; ++k) {
            minv[k] = FBIG;
            uacc[k] = 0.0f;
            wayr[k] = 0u;
            p_cache[k] = p[k * 64 + lane];          // phase-constant
            meta[k] = ((unsigned)(k * 64 + lane) << 10) | (unsigned)(p_cache[k] + 1);
        }
        int j0 = QQ;            // dummy column marker (== m)
        int jfree = -1;
        float ui0 = u[i];       // phase-start u of the new row
        float uu_i = ui0;       // running u[i] (dummy column's row)
        float4 G = tps[i];

        for (;;) {
            // relax fresh columns: cur = ((cc + cp) - u[i0]) - v[j], all f32
#pragma unroll
            for (int k = 0; k < 16; ++k) {
                int j = k * 64 + lane;
                float4 P = pps[j];
                float cp = ((fabsf(P.x - G.x) + fabsf(P.y - G.y))
                            + fabsf(P.z - G.z)) + fabsf(P.w - G.w);
                float c = dreg[k] + cp;
                float cur = (c - ui0) - v[k];
                bool fresh = !((used >> k) & 1u);
                bool upd = fresh && (cur < minv[k]);
                minv[k] = upd ? cur : minv[k];
                wayr[k] = upd ? (unsigned)j0 : wayr[k];   // (2) register way
            }
            // lane-local argmin over masked (used -> big); ascending-k scan
            float bv = 2e9f;
            unsigned bm = 0xFFFFFFFFu;
#pragma unroll
            for (int k = 0; k < 16; ++k) {
                float dv = ((used >> k) & 1u) ? FBIG : minv[k];
                if (dv < bv) { bv = dv; bm = meta[k]; }
            }
            // 64-lane DPP reduce to lane 63, then broadcast
            int bvI = __float_as_int(bv);
            unsigned bmU = bm;
            DPP_STEP(0x111)  // row_shr:1
            DPP_STEP(0x112)  // row_shr:2
            DPP_STEP(0x114)  // row_shr:4
            DPP_STEP(0x118)  // row_shr:8
            DPP_STEP(0x142)  // row_bcast:15
            DPP_STEP(0x143)  // row_bcast:31
            float delta = __int_as_float(__builtin_amdgcn_readlane(bvI, 63));
            unsigned wm = (unsigned)__builtin_amdgcn_readlane((int)bmU, 63);
            int j1 = (int)(wm >> 10);
            int pj1 = (int)(wm & 1023u) - 1;
            bool matched = (pj1 >= 0);

            // early uniform reads for next step (phase-start values; u[pj1]
            // untouched in-phase before j1's selection) — latency overlaps
            // the register update loop below
            float nui = 0.0f; float4 nG = G;
            if (matched) { nui = u[pj1]; nG = tps[pj1]; }

            // per-step updates exactly as reference (used excludes j1):
#pragma unroll
            for (int k = 0; k < 16; ++k) {
                if ((used >> k) & 1u) {
                    v[k] -= delta;
                    uacc[k] += delta;
                } else {
                    minv[k] -= delta;
                }
            }
            uu_i += delta;

            if (!matched) { jfree = j1; break; }

            // mark j1 used; snapshot its row's phase-start u into uacc
            unsigned selbit = (lane == (j1 & 63)) ? (1u << (j1 >> 6)) : 0u;
#pragma unroll
            for (int k = 0; k < 16; ++k)
                uacc[k] = ((selbit >> k) & 1u) ? nui : uacc[k];
            used |= selbit;
            j0 = j1;
            ui0 = nui;
            G = nG;
        }

        // phase epilogue: flush u and way for used columns, dummy row, jfree
#pragma unroll
        for (int k = 0; k < 16; ++k) {
            if ((used >> k) & 1u) {
                u[p_cache[k]] = uacc[k];
                way[k * 64 + lane] = (unsigned short)wayr[k];
            }
        }
        if (lane == (jfree & 63)) {
#pragma unroll
            for (int k = 0; k < 16; ++k)
                if (k == (jfree >> 6)) way[jfree] = (unsigned short)wayr[k];
        }
        if (lane == 0) u[i] = uu_i;

        // augment along predecessor chain (serial, lane 0)
        if (lane == 0) {
            int j = jfree;
            for (;;) {
                int jn = way[j];
                if (jn == QQ) { p[j] = i; break; }
                p[j] = p[jn];
                j = jn;
            }
        }
        __syncthreads();
    }

    // Output: ascending-j compaction == reference argsort(col4row).
    float* outr = out + (size_t)BB * QQ * TT + (size_t)b * TT;
    float* outc = outr + (size_t)BB * TT;
    int base = 0;
    for (int kb = 0; kb < 16; ++kb) {
        int j = kb * 64 + lane;
        int pj = p[j];
        bool a = pj >= 0;
        unsigned long long mask = __ballot(a);
        int rank = __popcll(mask & ((1ull << lane) - 1ull));
        if (a) {
            outr[base + rank] = (float)j;
            outc[base + rank] = (float)pj;
        }
        base += __popcll(mask);
    }
}

extern "C" void kernel_launch(void* const* d_in, const int* in_sizes, int n_in,
                              void* d_out, int out_size, void* d_ws, size_t ws_size,
                              hipStream_t stream) {
    const float* logits = (const float*)d_in[0];
    const float4* pp = (const float4*)d_in[1];
    const float4* tp = (const float4*)d_in[2];
    const int* labels = (const int*)d_in[3];
    float* out = (float*)d_out;

    int cls = in_sizes[0] / (BB * QQ);   // = 1 for this instance
    size_t total = (size_t)BB * QQ * TT;
    size_t diff_bytes = (size_t)in_sizes[0] * sizeof(float);

    if (ws_size >= diff_bytes) {
        float* diff = (float*)d_ws;
        int ndiff = in_sizes[0];
        diff_kernel<<<(ndiff + 255) / 256, 256, 0, stream>>>(logits, diff, ndiff);
        cost_kernel<<<(unsigned)((total + 255) / 256), 256, 0, stream>>>(
            diff, pp, tp, labels, out, cls, total);
    } else {
        cost_inline_kernel<<<(unsigned)((total + 255) / 256), 256, 0, stream>>>(
            logits, pp, tp, labels, out, cls, total);
    }

    lap_kernel<<<BB, 64, 0, stream>>>(logits, pp, tp, cls, out);
}